// Round 6
// baseline (731.441 us; speedup 1.0000x reference)
//
#include <hip/hip_runtime.h>
#include <hip/hip_bf16.h>

#define N_NODES 16000
#define N_EDGES 256000

// ---- workspace layout (float offsets) — total 288000 floats = 1.15 MB ----
#define OFF_SIM   0          // 256000  sim, later overwritten with attn (in-place, own slot)
#define OFF_MORD  256000     // 16000   per-dst max-sim, order-encoded uint32 (memset 0 = below-all sentinel)
#define OFF_Z     272000     // 16000

__device__ __forceinline__ unsigned ord_encode(float f) {
  unsigned b = __float_as_uint(f);
  return (b & 0x80000000u) ? ~b : (b | 0x80000000u);
}
__device__ __forceinline__ float ord_decode(unsigned e) {
  return __uint_as_float((e & 0x80000000u) ? (e & 0x7FFFFFFFu) : ~e);
}

__device__ __forceinline__ float dot16(const float* h, const float* w) {
  float r = 0.f;
#pragma unroll
  for (int t = 0; t < 16; ++t) r = fmaf(h[t], w[t], r);
  return r;
}

// load a 40-float row (rows are 160B = 16B-aligned) via 10 x float4
__device__ __forceinline__ void load_row40(const float* __restrict__ p, float* xr) {
  const float4* rp = reinterpret_cast<const float4*>(p);
#pragma unroll
  for (int q = 0; q < 10; ++q) {
    float4 f = rp[q];
    xr[4 * q + 0] = f.x; xr[4 * q + 1] = f.y; xr[4 * q + 2] = f.z; xr[4 * q + 3] = f.w;
  }
}

struct EdgeGeom { float vhx, vhy, vhz, y1x, y1y, y1z; };

// geometry + radial basis + h = silu(rad @ W1n); W1 (LDS) [b*16+t], pre-scaled by 1/sqrt(32)
__device__ __forceinline__ void edge_h(const float* __restrict__ pos, int s, int d,
                                       const float* W1, float* h, EdgeGeom& g) {
  float vx = pos[3 * d + 0] - pos[3 * s + 0];
  float vy = pos[3 * d + 1] - pos[3 * s + 1];
  float vz = pos[3 * d + 2] - pos[3 * s + 2];
  float dist = sqrtf(fmaf(vx, vx, fmaf(vy, vy, vz * vz)));
  float dsafe = fmaxf(dist, 1e-6f);
  float rinv = 1.0f / dsafe;
  g.vhx = vx * rinv; g.vhy = vy * rinv; g.vhz = vz * rinv;
  g.y1x = 1.7320508075688772f * g.vhx;
  g.y1y = 1.7320508075688772f * g.vhy;
  g.y1z = 1.7320508075688772f * g.vhz;
  float pre[16];
#pragma unroll
  for (int t = 0; t < 16; ++t) pre[t] = 0.f;
  // rad_b = sqrt(2/Rc)*sin((b+1)*pi*d/Rc)/d * mask(d<Rc) * sqrt(32); Chebyshev recurrence for sin(n x)
  float sx, cx;
  sincosf(1.2566370614359172f * dsafe, &sx, &cx);   // pi/R_CUT * dsafe
  cx = fminf(1.f, fmaxf(-1.f, cx));                 // recurrence stability
  float twoc = 2.f * cx;
  float sprev = 0.f, scur = sx;
  float rscale = (dist < 2.5f) ? (5.059644256269407f * rinv) : 0.f;  // sqrt(2/2.5)*sqrt(32)
#pragma unroll
  for (int b = 0; b < 32; ++b) {
    float radb = rscale * scur;
#pragma unroll
    for (int t = 0; t < 16; ++t) pre[t] = fmaf(radb, W1[16 * b + t], pre[t]);
    float snext = fmaf(twoc, scur, -sprev);
    sprev = scur; scur = snext;
  }
#pragma unroll
  for (int t = 0; t < 16; ++t) h[t] = pre[t] / (1.f + __expf(-pre[t]));  // silu
}

// ================= pass 1: q (on the fly) + k tensor-product + sim + per-dst max =================
// LDS (floats): [0,512) W1K/sqrt32 | [512,5120) W2K transposed [col*16+t]*(1/sqrt16/sqrt24)
//               [5120,5248) WQS*0.25 | [5248,5280) WQV/sqrt8
//               [5280,5344) WSS/sqrt80 | [5344,5360) WVV/(sqrt80*sqrt3)
__global__ void __launch_bounds__(256) k_edge1(
    const float* __restrict__ pos, const float* __restrict__ x,
    const float* __restrict__ Wq_s, const float* __restrict__ Wq_v,
    const float* __restrict__ Wk1, const float* __restrict__ Wk2,
    const float* __restrict__ Wss, const float* __restrict__ Wvv,
    const int* __restrict__ esrc, const int* __restrict__ edst,
    float* __restrict__ sim_out, unsigned* __restrict__ Mord) {
  __shared__ float L[5360];
  for (int i = threadIdx.x; i < 5360; i += 256) {
    float v;
    if (i < 512) v = Wk1[i] * 0.17677669529663687f;
    else if (i < 5120) {
      int j = i - 512; int col = j >> 4, t = j & 15;
      v = Wk2[t * 288 + col] * 0.051031036307982884f;
    }
    else if (i < 5248) v = Wq_s[i - 5120] * 0.25f;
    else if (i < 5280) v = Wq_v[i - 5248] * 0.3535533905932738f;
    else if (i < 5344) v = Wss[i - 5280] * 0.11180339887498948f;
    else               v = Wvv[i - 5344] * 0.06454972243679028f;
    L[i] = v;
  }
  __syncthreads();

  int e = blockIdx.x * 256 + threadIdx.x;   // 1000*256 = 256000 exact
  int s = esrc[e], d = edst[e];
  float h[16]; EdgeGeom g;
  edge_h(pos, s, d, L, h, g);

  float qd[8], qvd[12];
  {
    float xd[40];
    load_row40(x + 40 * d, xd);
#pragma unroll
    for (int o = 0; o < 8; ++o) qd[o] = 0.f;
#pragma unroll
    for (int i = 0; i < 16; ++i)
#pragma unroll
      for (int o = 0; o < 8; ++o) qd[o] = fmaf(xd[i], L[5120 + 8 * i + o], qd[o]);
#pragma unroll
    for (int k = 0; k < 12; ++k) qvd[k] = 0.f;
#pragma unroll
    for (int i = 0; i < 8; ++i)
#pragma unroll
      for (int o = 0; o < 4; ++o)
#pragma unroll
        for (int c = 0; c < 3; ++c)
          qvd[3 * o + c] = fmaf(xd[16 + 3 * i + c], L[5248 + 4 * i + o], qvd[3 * o + c]);
  }

  float xr[40];
  load_row40(x + 40 * s, xr);
  const float* xs = xr;
  const float* xv = xr + 16;
  float B[8];   // xv_i . vh
#pragma unroll
  for (int i = 0; i < 8; ++i)
    B[i] = fmaf(xv[3 * i], g.vhx, fmaf(xv[3 * i + 1], g.vhy, xv[3 * i + 2] * g.vhz));

  const float* W2 = L + 512;
  float ks[8];
#pragma unroll
  for (int o = 0; o < 8; ++o) {
    float acc = 0.f;
#pragma unroll
    for (int i = 0; i < 16; ++i) acc = fmaf(xs[i], dot16(h, W2 + ((i * 8 + o) << 4)), acc);
#pragma unroll
    for (int i = 0; i < 8; ++i)  acc = fmaf(B[i], dot16(h, W2 + ((128 + i * 8 + o) << 4)), acc);
    ks[o] = acc;
  }
  float kv[12];
#pragma unroll
  for (int o = 0; o < 4; ++o) {
    float s1 = 0.f;
#pragma unroll
    for (int i = 0; i < 16; ++i) s1 = fmaf(xs[i], dot16(h, W2 + ((192 + i * 4 + o) << 4)), s1);
    float s2x = 0.f, s2y = 0.f, s2z = 0.f;
#pragma unroll
    for (int i = 0; i < 8; ++i) {
      float w = dot16(h, W2 + ((256 + i * 4 + o) << 4));
      s2x = fmaf(xv[3 * i], w, s2x);
      s2y = fmaf(xv[3 * i + 1], w, s2y);
      s2z = fmaf(xv[3 * i + 2], w, s2z);
    }
    kv[3 * o]     = fmaf(g.y1x, s1, s2x);
    kv[3 * o + 1] = fmaf(g.y1y, s1, s2y);
    kv[3 * o + 2] = fmaf(g.y1z, s1, s2z);
  }

  float sim = 0.f;
#pragma unroll
  for (int j = 0; j < 8; ++j) {
    float t = 0.f;
#pragma unroll
    for (int i = 0; i < 8; ++i) t = fmaf(qd[i], L[5280 + 8 * i + j], t);
    sim = fmaf(t, ks[j], sim);
  }
#pragma unroll
  for (int j = 0; j < 4; ++j)
#pragma unroll
    for (int c = 0; c < 3; ++c) {
      float t = 0.f;
#pragma unroll
      for (int i = 0; i < 4; ++i) t = fmaf(qvd[3 * i + c], L[5344 + 4 * i + j], t);
      sim = fmaf(t, kv[3 * j + c], sim);
    }
  sim_out[e] = sim;
  atomicMax(&Mord[d], ord_encode(sim));
}

// ================= pass 1b: attn = exp(sim - M[dst]); Z += attn =================
__global__ void __launch_bounds__(256) k_attn(
    const int* __restrict__ edst, float* __restrict__ sim_attn,
    const unsigned* __restrict__ Mord, float* __restrict__ Z) {
  int e = blockIdx.x * 256 + threadIdx.x;
  int d = edst[e];
  float m = ord_decode(Mord[d]);        // >= sim[e] by construction
  float at = __expf(sim_attn[e] - m);   // in (0, 1]
  sim_attn[e] = at;                     // own slot, in-place
  atomicAdd(&Z[d], at);
}

// ================= pass 2: v tensor-product + a = attn/Z + scatter a*v into d_out (fp32) ==========
// LDS: [0,512) W1V/sqrt32 | [512,9728) W2V transposed [col*16+t]*(1/sqrt16/sqrt24)
__global__ void __launch_bounds__(256) k_edge2(
    const float* __restrict__ pos, const float* __restrict__ x,
    const float* __restrict__ Wv1, const float* __restrict__ Wv2,
    const int* __restrict__ esrc, const int* __restrict__ edst,
    const float* __restrict__ attn, const float* __restrict__ Z,
    float* __restrict__ out) {
  __shared__ float L[9728];
  for (int i = threadIdx.x; i < 9728; i += 256) {
    float v;
    if (i < 512) v = Wv1[i] * 0.17677669529663687f;
    else {
      int j = i - 512; int col = j >> 4, t = j & 15;
      v = Wv2[t * 576 + col] * 0.051031036307982884f;
    }
    L[i] = v;
  }
  __syncthreads();

  int e = blockIdx.x * 256 + threadIdx.x;
  int s = esrc[e], d = edst[e];
  float h[16]; EdgeGeom g;
  edge_h(pos, s, d, L, h, g);
  float xr[40];
  load_row40(x + 40 * s, xr);
  const float* xs = xr;
  const float* xv = xr + 16;
  float B[8];
#pragma unroll
  for (int i = 0; i < 8; ++i)
    B[i] = fmaf(xv[3 * i], g.vhx, fmaf(xv[3 * i + 1], g.vhy, xv[3 * i + 2] * g.vhz));

  float a = attn[e] / Z[d];   // attn in (0,1], Z >= 1  =>  a in [0,1]
  const float* W2 = L + 512;
  float* op = out + 40 * d;
#pragma unroll
  for (int o = 0; o < 16; ++o) {
    float acc = 0.f;
#pragma unroll
    for (int i = 0; i < 16; ++i) acc = fmaf(xs[i], dot16(h, W2 + ((i * 16 + o) << 4)), acc);
#pragma unroll
    for (int i = 0; i < 8; ++i)  acc = fmaf(B[i], dot16(h, W2 + ((256 + i * 16 + o) << 4)), acc);
    atomicAdd(op + o, a * acc);
  }
#pragma unroll
  for (int o = 0; o < 8; ++o) {
    float s1 = 0.f;
#pragma unroll
    for (int i = 0; i < 16; ++i) s1 = fmaf(xs[i], dot16(h, W2 + ((384 + i * 8 + o) << 4)), s1);
    float s2x = 0.f, s2y = 0.f, s2z = 0.f;
#pragma unroll
    for (int i = 0; i < 8; ++i) {
      float w = dot16(h, W2 + ((512 + i * 8 + o) << 4));
      s2x = fmaf(xv[3 * i], w, s2x);
      s2y = fmaf(xv[3 * i + 1], w, s2y);
      s2z = fmaf(xv[3 * i + 2], w, s2z);
    }
    atomicAdd(op + 16 + 3 * o,     a * fmaf(g.y1x, s1, s2x));
    atomicAdd(op + 16 + 3 * o + 1, a * fmaf(g.y1y, s1, s2y));
    atomicAdd(op + 16 + 3 * o + 2, a * fmaf(g.y1z, s1, s2z));
  }
}

extern "C" void kernel_launch(void* const* d_in, const int* in_sizes, int n_in,
                              void* d_out, int out_size, void* d_ws, size_t ws_size,
                              hipStream_t stream) {
  (void)in_sizes; (void)n_in; (void)out_size; (void)ws_size;
  const float* pos  = (const float*)d_in[0];
  const float* x    = (const float*)d_in[1];
  const float* Wq_s = (const float*)d_in[2];
  const float* Wq_v = (const float*)d_in[3];
  const float* Wk1  = (const float*)d_in[4];
  const float* Wk2  = (const float*)d_in[5];
  const float* Wv1  = (const float*)d_in[6];
  const float* Wv2  = (const float*)d_in[7];
  const float* Wss  = (const float*)d_in[8];
  const float* Wvv  = (const float*)d_in[9];
  const int* esrc = (const int*)d_in[10];
  const int* edst = (const int*)d_in[11];
  float* ws = (float*)d_ws;
  float* out = (float*)d_out;   // fp32 output (reference returns jnp.float32)

  // zero Mord + Z (Mord=0 is the below-all-floats sentinel) and the fp32 output (re-poisoned 0xAA each replay)
  hipMemsetAsync(ws + OFF_MORD, 0, (size_t)(16000 + 16000) * sizeof(float), stream);
  hipMemsetAsync(out, 0, (size_t)(N_NODES * 40) * sizeof(float), stream);
  k_edge1<<<1000, 256, 0, stream>>>(pos, x, Wq_s, Wq_v, Wk1, Wk2, Wss, Wvv,
                                    esrc, edst, ws + OFF_SIM, (unsigned*)(ws + OFF_MORD));
  k_attn<<<1000, 256, 0, stream>>>(edst, ws + OFF_SIM, (const unsigned*)(ws + OFF_MORD), ws + OFF_Z);
  k_edge2<<<1000, 256, 0, stream>>>(pos, x, Wv1, Wv2, esrc, edst,
                                    ws + OFF_SIM, ws + OFF_Z, out);
}

// Round 7
// 314.521 us; speedup vs baseline: 2.3256x; 2.3256x over previous
//
#include <hip/hip_runtime.h>
#include <hip/hip_bf16.h>

#define N_NODES 16000
#define N_EDGES 256000

// ---- workspace layout (4-byte units) — total 816001 * 4B = 3.26 MB ----
#define OFF_SRCB   0          // int   256000  src per CSR slot
#define OFF_DSTB   256000     // int   256000  dst per CSR slot (sorted ascending by construction)
#define OFF_SIMB   512000     // float 256000  raw sim -> normalized a (in place)
#define OFF_CNT    768000     // int   16000   per-dst degree
#define OFF_START  784000     // int   16001   CSR row offsets (exclusive scan; [16000] = 256000)
#define OFF_CUR    800001     // int   16000   fill cursors (scan initializes = start)

__device__ __forceinline__ float dot16(const float* h, const float* w) {
  float r = 0.f;
#pragma unroll
  for (int t = 0; t < 16; ++t) r = fmaf(h[t], w[t], r);
  return r;
}

// load a 40-float row (rows are 160B = 16B-aligned) via 10 x float4
__device__ __forceinline__ void load_row40(const float* __restrict__ p, float* xr) {
  const float4* rp = reinterpret_cast<const float4*>(p);
#pragma unroll
  for (int q = 0; q < 10; ++q) {
    float4 f = rp[q];
    xr[4 * q + 0] = f.x; xr[4 * q + 1] = f.y; xr[4 * q + 2] = f.z; xr[4 * q + 3] = f.w;
  }
}

struct EdgeGeom { float vhx, vhy, vhz, y1x, y1y, y1z; };

// geometry + radial basis + h = silu(rad @ W1n); W1 (LDS) [b*16+t], pre-scaled by 1/sqrt(32)
__device__ __forceinline__ void edge_h(const float* __restrict__ pos, int s, int d,
                                       const float* W1, float* h, EdgeGeom& g) {
  float vx = pos[3 * d + 0] - pos[3 * s + 0];
  float vy = pos[3 * d + 1] - pos[3 * s + 1];
  float vz = pos[3 * d + 2] - pos[3 * s + 2];
  float dist = sqrtf(fmaf(vx, vx, fmaf(vy, vy, vz * vz)));
  float dsafe = fmaxf(dist, 1e-6f);
  float rinv = 1.0f / dsafe;
  g.vhx = vx * rinv; g.vhy = vy * rinv; g.vhz = vz * rinv;
  g.y1x = 1.7320508075688772f * g.vhx;
  g.y1y = 1.7320508075688772f * g.vhy;
  g.y1z = 1.7320508075688772f * g.vhz;
  float pre[16];
#pragma unroll
  for (int t = 0; t < 16; ++t) pre[t] = 0.f;
  float sx, cx;
  sincosf(1.2566370614359172f * dsafe, &sx, &cx);   // pi/R_CUT * dsafe
  cx = fminf(1.f, fmaxf(-1.f, cx));
  float twoc = 2.f * cx;
  float sprev = 0.f, scur = sx;
  float rscale = (dist < 2.5f) ? (5.059644256269407f * rinv) : 0.f;  // sqrt(2/2.5)*sqrt(32)
#pragma unroll
  for (int b = 0; b < 32; ++b) {
    float radb = rscale * scur;
#pragma unroll
    for (int t = 0; t < 16; ++t) pre[t] = fmaf(radb, W1[16 * b + t], pre[t]);
    float snext = fmaf(twoc, scur, -sprev);
    sprev = scur; scur = snext;
  }
#pragma unroll
  for (int t = 0; t < 16; ++t) h[t] = pre[t] / (1.f + __expf(-pre[t]));  // silu
}

// ================= CSR build =================
__global__ void k_hist(const int* __restrict__ edst, int* __restrict__ cnt) {
  int e = blockIdx.x * 256 + threadIdx.x;
  atomicAdd(&cnt[edst[e]], 1);
}

// single block, 1024 threads: exclusive scan of cnt[16000] -> start[16001]; cur = start
__global__ void __launch_bounds__(1024) k_scan(const int* __restrict__ cnt,
                                               int* __restrict__ start, int* __restrict__ cur) {
  __shared__ int part[1024];
  int t = threadIdx.x;
  int base = t * 16;
  int local[16];
  int sum = 0;
#pragma unroll
  for (int i = 0; i < 16; ++i) {
    int idx = base + i;
    int c = (idx < N_NODES) ? cnt[idx] : 0;
    local[i] = sum; sum += c;
  }
  part[t] = sum;
  __syncthreads();
  for (int off = 1; off < 1024; off <<= 1) {
    int v = (t >= off) ? part[t - off] : 0;
    __syncthreads();
    part[t] += v;
    __syncthreads();
  }
  int prev = (t == 0) ? 0 : part[t - 1];
#pragma unroll
  for (int i = 0; i < 16; ++i) {
    int idx = base + i;
    if (idx < N_NODES) { int st = prev + local[i]; start[idx] = st; cur[idx] = st; }
  }
  if (t == 0) start[N_NODES] = N_EDGES;
}

__global__ void k_fill(const int* __restrict__ esrc, const int* __restrict__ edst,
                       int* __restrict__ cur, int* __restrict__ srcb, int* __restrict__ dstb) {
  int e = blockIdx.x * 256 + threadIdx.x;
  int d = edst[e];
  int slot = atomicAdd(&cur[d], 1);
  srcb[slot] = esrc[e];
  dstb[slot] = d;
}

// ================= pass 1 (slot-parallel): q + k tensor-product + raw sim =================
// LDS (floats): [0,512) W1K/sqrt32 | [512,5120) W2K transposed [col*16+t]*(1/sqrt16/sqrt24)
//               [5120,5248) WQS*0.25 | [5248,5280) WQV/sqrt8
//               [5280,5344) WSS/sqrt80 | [5344,5360) WVV/(sqrt80*sqrt3)
__global__ void __launch_bounds__(256) k_edge1(
    const float* __restrict__ pos, const float* __restrict__ x,
    const float* __restrict__ Wq_s, const float* __restrict__ Wq_v,
    const float* __restrict__ Wk1, const float* __restrict__ Wk2,
    const float* __restrict__ Wss, const float* __restrict__ Wvv,
    const int* __restrict__ srcb, const int* __restrict__ dstb,
    float* __restrict__ simb) {
  __shared__ float L[5360];
  for (int i = threadIdx.x; i < 5360; i += 256) {
    float v;
    if (i < 512) v = Wk1[i] * 0.17677669529663687f;
    else if (i < 5120) {
      int j = i - 512; int col = j >> 4, t = j & 15;
      v = Wk2[t * 288 + col] * 0.051031036307982884f;
    }
    else if (i < 5248) v = Wq_s[i - 5120] * 0.25f;
    else if (i < 5280) v = Wq_v[i - 5248] * 0.3535533905932738f;
    else if (i < 5344) v = Wss[i - 5280] * 0.11180339887498948f;
    else               v = Wvv[i - 5344] * 0.06454972243679028f;
    L[i] = v;
  }
  __syncthreads();

  int j = blockIdx.x * 256 + threadIdx.x;   // CSR slot
  int s = srcb[j], d = dstb[j];
  float h[16]; EdgeGeom g;
  edge_h(pos, s, d, L, h, g);

  float qd[8], qvd[12];
  {
    float xd[40];
    load_row40(x + 40 * d, xd);   // consecutive slots share d -> L1-resident
#pragma unroll
    for (int o = 0; o < 8; ++o) qd[o] = 0.f;
#pragma unroll
    for (int i = 0; i < 16; ++i)
#pragma unroll
      for (int o = 0; o < 8; ++o) qd[o] = fmaf(xd[i], L[5120 + 8 * i + o], qd[o]);
#pragma unroll
    for (int k = 0; k < 12; ++k) qvd[k] = 0.f;
#pragma unroll
    for (int i = 0; i < 8; ++i)
#pragma unroll
      for (int o = 0; o < 4; ++o)
#pragma unroll
        for (int c = 0; c < 3; ++c)
          qvd[3 * o + c] = fmaf(xd[16 + 3 * i + c], L[5248 + 4 * i + o], qvd[3 * o + c]);
  }

  float xr[40];
  load_row40(x + 40 * s, xr);
  const float* xs = xr;
  const float* xv = xr + 16;
  float B[8];
#pragma unroll
  for (int i = 0; i < 8; ++i)
    B[i] = fmaf(xv[3 * i], g.vhx, fmaf(xv[3 * i + 1], g.vhy, xv[3 * i + 2] * g.vhz));

  const float* W2 = L + 512;
  float ks[8];
#pragma unroll
  for (int o = 0; o < 8; ++o) {
    float acc = 0.f;
#pragma unroll
    for (int i = 0; i < 16; ++i) acc = fmaf(xs[i], dot16(h, W2 + ((i * 8 + o) << 4)), acc);
#pragma unroll
    for (int i = 0; i < 8; ++i)  acc = fmaf(B[i], dot16(h, W2 + ((128 + i * 8 + o) << 4)), acc);
    ks[o] = acc;
  }
  float kv[12];
#pragma unroll
  for (int o = 0; o < 4; ++o) {
    float s1 = 0.f;
#pragma unroll
    for (int i = 0; i < 16; ++i) s1 = fmaf(xs[i], dot16(h, W2 + ((192 + i * 4 + o) << 4)), s1);
    float s2x = 0.f, s2y = 0.f, s2z = 0.f;
#pragma unroll
    for (int i = 0; i < 8; ++i) {
      float w = dot16(h, W2 + ((256 + i * 4 + o) << 4));
      s2x = fmaf(xv[3 * i], w, s2x);
      s2y = fmaf(xv[3 * i + 1], w, s2y);
      s2z = fmaf(xv[3 * i + 2], w, s2z);
    }
    kv[3 * o]     = fmaf(g.y1x, s1, s2x);
    kv[3 * o + 1] = fmaf(g.y1y, s1, s2y);
    kv[3 * o + 2] = fmaf(g.y1z, s1, s2z);
  }

  float sim = 0.f;
#pragma unroll
  for (int jj = 0; jj < 8; ++jj) {
    float t = 0.f;
#pragma unroll
    for (int i = 0; i < 8; ++i) t = fmaf(qd[i], L[5280 + 8 * i + jj], t);
    sim = fmaf(t, ks[jj], sim);
  }
#pragma unroll
  for (int jj = 0; jj < 4; ++jj)
#pragma unroll
    for (int c = 0; c < 3; ++c) {
      float t = 0.f;
#pragma unroll
      for (int i = 0; i < 4; ++i) t = fmaf(qvd[3 * i + c], L[5344 + 4 * i + jj], t);
      sim = fmaf(t, kv[3 * jj + c], sim);
    }
  simb[j] = sim;
}

// ================= exact per-dst softmax: simb <- exp(sim - max)/Z =================
__global__ void k_norm(const int* __restrict__ start, float* __restrict__ simb) {
  int n = blockIdx.x * 256 + threadIdx.x;
  if (n >= N_NODES) return;
  int a = start[n], b = start[n + 1];
  if (a == b) return;
  float m = -3.4e38f;
  for (int j = a; j < b; ++j) m = fmaxf(m, simb[j]);
  float Z = 0.f;
  for (int j = a; j < b; ++j) { float t = __expf(simb[j] - m); simb[j] = t; Z += t; }
  float inv = 1.f / Z;
  for (int j = a; j < b; ++j) simb[j] *= inv;
}

// ================= pass 2 (slot-parallel): v TP + wave-segmented scatter =================
// LDS: [0,512) W1V/sqrt32 | [512,9728) W2V transposed [col*16+t]*(1/sqrt16/sqrt24)
__global__ void __launch_bounds__(256) k_edge2(
    const float* __restrict__ pos, const float* __restrict__ x,
    const float* __restrict__ Wv1, const float* __restrict__ Wv2,
    const int* __restrict__ srcb, const int* __restrict__ dstb,
    const float* __restrict__ ab, float* __restrict__ out) {
  __shared__ float L[9728];
  for (int i = threadIdx.x; i < 9728; i += 256) {
    float v;
    if (i < 512) v = Wv1[i] * 0.17677669529663687f;
    else {
      int j = i - 512; int col = j >> 4, t = j & 15;
      v = Wv2[t * 576 + col] * 0.051031036307982884f;
    }
    L[i] = v;
  }
  __syncthreads();

  int j = blockIdx.x * 256 + threadIdx.x;   // CSR slot (sorted by dst)
  int s = srcb[j], d = dstb[j];
  int lane = threadIdx.x & 63;

  // wave-segmented-reduction masks (dst runs are contiguous)
  bool same[6];
#pragma unroll
  for (int k = 0; k < 6; ++k) {
    int dd = __shfl_down(d, 1 << k, 64);
    same[k] = ((lane + (1 << k)) < 64) && (dd == d);
  }
  int dprev = __shfl_up(d, 1, 64);
  bool head = (lane == 0) || (dprev != d);

  float h[16]; EdgeGeom g;
  edge_h(pos, s, d, L, h, g);
  float xr[40];
  load_row40(x + 40 * s, xr);
  const float* xs = xr;
  const float* xv = xr + 16;
  float B[8];
#pragma unroll
  for (int i = 0; i < 8; ++i)
    B[i] = fmaf(xv[3 * i], g.vhx, fmaf(xv[3 * i + 1], g.vhy, xv[3 * i + 2] * g.vhz));

  float a = ab[j];            // normalized attention weight in [0,1]
  const float* W2 = L + 512;
  float* op = out + 40 * d;

#pragma unroll
  for (int o = 0; o < 16; ++o) {
    float acc = 0.f;
#pragma unroll
    for (int i = 0; i < 16; ++i) acc = fmaf(xs[i], dot16(h, W2 + ((i * 16 + o) << 4)), acc);
#pragma unroll
    for (int i = 0; i < 8; ++i)  acc = fmaf(B[i], dot16(h, W2 + ((256 + i * 16 + o) << 4)), acc);
    float v = a * acc;
#pragma unroll
    for (int k = 0; k < 6; ++k) {
      float ov = __shfl_down(v, 1 << k, 64);
      v += same[k] ? ov : 0.f;
    }
    if (head) atomicAdd(op + o, v);
  }
#pragma unroll
  for (int o = 0; o < 8; ++o) {
    float s1 = 0.f;
#pragma unroll
    for (int i = 0; i < 16; ++i) s1 = fmaf(xs[i], dot16(h, W2 + ((384 + i * 8 + o) << 4)), s1);
    float s2x = 0.f, s2y = 0.f, s2z = 0.f;
#pragma unroll
    for (int i = 0; i < 8; ++i) {
      float w = dot16(h, W2 + ((512 + i * 8 + o) << 4));
      s2x = fmaf(xv[3 * i], w, s2x);
      s2y = fmaf(xv[3 * i + 1], w, s2y);
      s2z = fmaf(xv[3 * i + 2], w, s2z);
    }
    float vc[3];
    vc[0] = a * fmaf(g.y1x, s1, s2x);
    vc[1] = a * fmaf(g.y1y, s1, s2y);
    vc[2] = a * fmaf(g.y1z, s1, s2z);
#pragma unroll
    for (int c = 0; c < 3; ++c) {
      float v = vc[c];
#pragma unroll
      for (int k = 0; k < 6; ++k) {
        float ov = __shfl_down(v, 1 << k, 64);
        v += same[k] ? ov : 0.f;
      }
      if (head) atomicAdd(op + 16 + 3 * o + c, v);
    }
  }
}

extern "C" void kernel_launch(void* const* d_in, const int* in_sizes, int n_in,
                              void* d_out, int out_size, void* d_ws, size_t ws_size,
                              hipStream_t stream) {
  (void)in_sizes; (void)n_in; (void)out_size; (void)ws_size;
  const float* pos  = (const float*)d_in[0];
  const float* x    = (const float*)d_in[1];
  const float* Wq_s = (const float*)d_in[2];
  const float* Wq_v = (const float*)d_in[3];
  const float* Wk1  = (const float*)d_in[4];
  const float* Wk2  = (const float*)d_in[5];
  const float* Wv1  = (const float*)d_in[6];
  const float* Wv2  = (const float*)d_in[7];
  const float* Wss  = (const float*)d_in[8];
  const float* Wvv  = (const float*)d_in[9];
  const int* esrc = (const int*)d_in[10];
  const int* edst = (const int*)d_in[11];
  int*   wsi  = (int*)d_ws;
  float* wsf  = (float*)d_ws;
  float* out  = (float*)d_out;

  int*   srcb  = wsi + OFF_SRCB;
  int*   dstb  = wsi + OFF_DSTB;
  float* simb  = wsf + OFF_SIMB;
  int*   cnt   = wsi + OFF_CNT;
  int*   start = wsi + OFF_START;
  int*   cur   = wsi + OFF_CUR;

  hipMemsetAsync(cnt, 0, (size_t)N_NODES * sizeof(int), stream);
  hipMemsetAsync(out, 0, (size_t)(N_NODES * 40) * sizeof(float), stream);
  k_hist<<<1000, 256, 0, stream>>>(edst, cnt);
  k_scan<<<1, 1024, 0, stream>>>(cnt, start, cur);
  k_fill<<<1000, 256, 0, stream>>>(esrc, edst, cur, srcb, dstb);
  k_edge1<<<1000, 256, 0, stream>>>(pos, x, Wq_s, Wq_v, Wk1, Wk2, Wss, Wvv,
                                    srcb, dstb, simb);
  k_norm<<<63, 256, 0, stream>>>(start, simb);
  k_edge2<<<1000, 256, 0, stream>>>(pos, x, Wv1, Wv2, srcb, dstb, simb, out);
}